// Round 1
// baseline (582.794 us; speedup 1.0000x reference)
//
#include <hip/hip_runtime.h>
#include <hip/hip_bf16.h>
#include <stdint.h>

// ---------------- problem constants ----------------
#define T_TOK  16384   // B*S
#define DMODEL 1024
#define NEXP   8
#define HDIM   2048
#define CAPSL  16512   // per-expert list capacity (max possible = T_TOK)

// GEMM tiling (m97 recipe: 128x128 tile, BK=64, 4 waves, global_load_lds w16)
#define BM 128
#define BN 128
#define BK 64
#define NWORK_MAX 264            // sum_e ceil(N_e/128) <= 32768/128 + 8
#define YROWS_MAX (NWORK_MAX*BM)

// ---------------- workspace layout (bytes) ----------------
#define OFF_COUNTS 0                   // int[8]
#define OFF_NWORK  64                  // int
#define OFF_FSUM   128                 // float[8]
#define OFF_PSUM   192                 // float[8]
#define OFF_WORK   256                 // int4[NWORK_MAX]
#define OFF_HSUM   8192                // float[NEXP*HDIM] = 64KB
#define OFF_ZERO_END 73728             // memset range [0, OFF_ZERO_END)
#define OFF_TOK    131072              // int[NEXP*CAPSL]
#define OFF_WGT    786432              // float[NEXP*CAPSL]
#define OFF_WT     2097152             // bf16 WgT then WuT, each [NEXP*HDIM*DMODEL]
#define WT_ELEMS   (NEXP*HDIM*DMODEL)  // 16.7M elems
#define OFF_Y      (OFF_WT + (size_t)2*WT_ELEMS*2)          // 69,206,016
#define NEED_FAST  (OFF_Y + (size_t)YROWS_MAX*DMODEL*2)     // ~138.4 MB

typedef __attribute__((ext_vector_type(4))) float f32x4;
typedef __attribute__((ext_vector_type(8))) short bf16x8;

__device__ __forceinline__ unsigned short f2bf(float f) {
    unsigned int u = __builtin_bit_cast(unsigned int, f);
    unsigned int r = (u + 0x7fffu + ((u >> 16) & 1u)) >> 16;
    return (unsigned short)r;
}

__device__ __forceinline__ void glds16(const void* g, void* l) {
    // width-16 global->LDS DMA; LDS dest must be wave-uniform (linear lane*16 fill)
    __builtin_amdgcn_global_load_lds((const __attribute__((address_space(1))) void*)g,
                                     (__attribute__((address_space(3))) void*)l, 16, 0, 0);
}

// ---------------- 1) weight transpose: f32 [E][D][H] -> bf16 [E][H][D] ----------------
__global__ __launch_bounds__(256) void wt_transpose(const float* __restrict__ wg,
                                                    const float* __restrict__ wu,
                                                    unsigned short* __restrict__ wt_out) {
    int mat = blockIdx.z;
    const float* src = mat ? wu : wg;
    unsigned short* dst = wt_out + (size_t)mat * WT_ELEMS;
    int e  = blockIdx.y;
    int kt = blockIdx.x & 15;   // D/64
    int ht = blockIdx.x >> 4;   // H/64
    __shared__ unsigned short tile[64][68];
    const float* s = src + ((size_t)e * DMODEL + kt * 64) * HDIM + ht * 64;
    for (int u = threadIdx.x; u < 1024; u += 256) {
        int r = u >> 4, c = (u & 15) * 4;
        float4 v = *(const float4*)(s + (size_t)r * HDIM + c);
        tile[r][c + 0] = f2bf(v.x); tile[r][c + 1] = f2bf(v.y);
        tile[r][c + 2] = f2bf(v.z); tile[r][c + 3] = f2bf(v.w);
    }
    __syncthreads();
    unsigned short* d = dst + ((size_t)e * HDIM + ht * 64) * DMODEL + kt * 64;
    for (int u = threadIdx.x; u < 1024; u += 256) {
        int r = u >> 4, c = (u & 15) * 4;      // r: h-local row, c: k-local col
        ushort4 o;
        o.x = tile[c + 0][r]; o.y = tile[c + 1][r];
        o.z = tile[c + 2][r]; o.w = tile[c + 3][r];
        *(ushort4*)(d + (size_t)r * DMODEL + c) = o;
    }
}

// ---------------- 2) gating: logits, top-2, aux partials, compacted lists ----------------
__global__ __launch_bounds__(256) void gating(const float* __restrict__ x,
                                              const float* __restrict__ gw,
                                              int* counts, float* fsum, float* psum,
                                              int* tok_list, float* wgt_list) {
    __shared__ float gws_t[NEXP * DMODEL];  // transposed [e][k], 32KB (conflict-free reads)
    __shared__ int   ch_e[64][2];
    __shared__ float ch_w[64][2];
    __shared__ float pacc[NEXP];
    __shared__ int   hist[NEXP], gbase[NEXP], cursor[NEXP];
    if (threadIdx.x < NEXP) { pacc[threadIdx.x] = 0.f; hist[threadIdx.x] = 0; cursor[threadIdx.x] = 0; }
    for (int u = threadIdx.x; u < NEXP * DMODEL; u += 256) {
        // u = k*8+e in source; scatter to [e][k]
        gws_t[(u & 7) * DMODEL + (u >> 3)] = gw[u];
    }
    __syncthreads();
    int wave = threadIdx.x >> 6, lane = threadIdx.x & 63;
    int tbase = blockIdx.x * 64;
    for (int it = 0; it < 16; ++it) {
        int slot = wave * 16 + it;
        int t = tbase + slot;
        float p[8] = {0, 0, 0, 0, 0, 0, 0, 0};
        #pragma unroll
        for (int j = 0; j < 16; ++j) {
            float xv = x[(size_t)t * DMODEL + j * 64 + lane];
            #pragma unroll
            for (int e2 = 0; e2 < 8; ++e2) p[e2] += xv * gws_t[e2 * DMODEL + j * 64 + lane];
        }
        #pragma unroll
        for (int off = 32; off >= 1; off >>= 1) {
            #pragma unroll
            for (int e2 = 0; e2 < 8; ++e2) p[e2] += __shfl_xor(p[e2], off);
        }
        if (lane == 0) {
            int i0 = 0; float l0 = p[0];
            #pragma unroll
            for (int e2 = 1; e2 < 8; ++e2) if (p[e2] > l0) { l0 = p[e2]; i0 = e2; }
            int i1 = -1; float l1 = -1e30f;
            #pragma unroll
            for (int e2 = 0; e2 < 8; ++e2) if (e2 != i0 && p[e2] > l1) { l1 = p[e2]; i1 = e2; }
            float a = __expf(l1 - l0);
            float w0 = 1.f / (1.f + a);
            ch_e[slot][0] = i0; ch_e[slot][1] = i1;
            ch_w[slot][0] = w0; ch_w[slot][1] = a * w0;
            atomicAdd(&hist[i0], 1); atomicAdd(&hist[i1], 1);
            float s = 0.f, ex[8];
            #pragma unroll
            for (int e2 = 0; e2 < 8; ++e2) { ex[e2] = __expf(p[e2] - l0); s += ex[e2]; }
            float inv = 1.f / s;
            #pragma unroll
            for (int e2 = 0; e2 < 8; ++e2) atomicAdd(&pacc[e2], ex[e2] * inv);
        }
    }
    __syncthreads();
    if (threadIdx.x < NEXP) {
        int h = hist[threadIdx.x];
        gbase[threadIdx.x] = atomicAdd(&counts[threadIdx.x], h);
        atomicAdd(&fsum[threadIdx.x], (float)h);
        atomicAdd(&psum[threadIdx.x], pacc[threadIdx.x]);
    }
    __syncthreads();
    if (threadIdx.x < 64) {
        int slot = threadIdx.x, t = tbase + slot;
        #pragma unroll
        for (int k2 = 0; k2 < 2; ++k2) {
            int e2 = ch_e[slot][k2];
            int pos = gbase[e2] + atomicAdd(&cursor[e2], 1);
            tok_list[e2 * CAPSL + pos] = t;
            wgt_list[e2 * CAPSL + pos] = ch_w[slot][k2];
        }
    }
}

// ---------------- 3) worklist + aux loss ----------------
__global__ void build_work(const int* counts, int4* work, int* n_work,
                           const float* fsum, const float* psum, float* out_aux) {
    if (threadIdx.x == 0 && blockIdx.x == 0) {
        int nw = 0, yb = 0;
        for (int e = 0; e < NEXP; ++e) {
            int c = counts[e];
            int nt = (c + BM - 1) / BM;
            for (int r = 0; r < nt; ++r) { work[nw] = make_int4(e, r * BM, yb, 0); yb += BM; ++nw; }
        }
        *n_work = nw;
        float aux = 0.f;
        for (int e = 0; e < NEXP; ++e)
            aux += (fsum[e] / (float)T_TOK) * (psum[e] / (float)T_TOK);
        *out_aux = aux * (float)(NEXP * NEXP);
    }
}

// ---------------- 4) materialize gathered+scaled Y as bf16 (FAST path) ----------------
__global__ __launch_bounds__(256) void materialize(const float* __restrict__ x,
                                                   const int* __restrict__ tok_list,
                                                   const float* __restrict__ wgt_list,
                                                   const int* __restrict__ counts,
                                                   const int4* __restrict__ work,
                                                   const int* __restrict__ n_work,
                                                   unsigned short* __restrict__ ybuf) {
    int w = blockIdx.x; if (w >= *n_work) return;
    int4 wi = work[w];
    int e = wi.x, row0 = wi.y, yb = wi.z;
    int cnt = counts[e];
    for (int u = threadIdx.x; u < BM * 256; u += 256) {   // one ushort4 per unit; 256 units/row
        int r = u >> 8, c = (u & 255) * 4;
        int slot = row0 + r;
        ushort4 o;
        if (slot < cnt) {
            int t = tok_list[e * CAPSL + slot];
            float wgt = wgt_list[e * CAPSL + slot];
            float4 v = *(const float4*)(x + (size_t)t * DMODEL + c);
            o.x = f2bf(v.x * wgt); o.y = f2bf(v.y * wgt);
            o.z = f2bf(v.z * wgt); o.w = f2bf(v.w * wgt);
        } else { o.x = o.y = o.z = o.w = 0; }
        *(ushort4*)(ybuf + (size_t)(yb + r) * DMODEL + c) = o;
    }
}

// ---------------- 5) fused dual-GEMM: G=Y@Wg, U=Y@Wu, hsum += colsum(silu(G)*U) ----------------
template <bool YMAT>
__global__ __launch_bounds__(256, 2) void moe_gemm(
        const unsigned short* __restrict__ ybuf,
        const float* __restrict__ x,
        const int* __restrict__ tok_list, const float* __restrict__ wgt_list,
        const unsigned short* __restrict__ wt,   // [2][E][H][D] bf16
        const int* __restrict__ counts,
        const int4* __restrict__ work, const int* __restrict__ n_work,
        float* __restrict__ hsum) {
    int w = blockIdx.x; if (w >= *n_work) return;
    int4 wi = work[w];
    int e = wi.x, row0 = wi.y, yb = wi.z;
    int n0 = blockIdx.y * BN;
    __shared__ unsigned short yl[BM * BK];
    __shared__ unsigned short gl[BN * BK];
    __shared__ unsigned short ul[BN * BK];
    __shared__ float red[4][64];
    int tid = threadIdx.x, wave = tid >> 6, lane = tid & 63;
    int wm = wave >> 1, wn = wave & 1;
    f32x4 accg[4][4], accu[4][4];
    #pragma unroll
    for (int mi = 0; mi < 4; ++mi)
        #pragma unroll
        for (int ni = 0; ni < 4; ++ni) {
            accg[mi][ni] = (f32x4){0.f, 0.f, 0.f, 0.f};
            accu[mi][ni] = (f32x4){0.f, 0.f, 0.f, 0.f};
        }
    const unsigned short* wg_base = wt + ((size_t)e * HDIM + n0) * DMODEL;
    const unsigned short* wu_base = wg_base + (size_t)WT_ELEMS;
    const unsigned short* y_base  = ybuf + (size_t)yb * DMODEL;

    int m_t = 0; float m_w = 0.f; bool m_valid = false;
    if (!YMAT) {
        int slot = row0 + (tid >> 1);
        int cnt = counts[e];
        m_valid = slot < cnt;
        if (m_valid) { m_t = tok_list[e * CAPSL + slot]; m_w = wgt_list[e * CAPSL + slot]; }
    }
    int lrow8 = lane >> 3, lcol = (lane & 7) * 8;

    for (int k0 = 0; k0 < DMODEL; k0 += BK) {
        #pragma unroll
        for (int c = 0; c < 4; ++c) {
            int r  = wave * 32 + c * 8;      // wave-uniform LDS base row
            int rr = r + lrow8;              // per-lane source row
            glds16(wg_base + (size_t)rr * DMODEL + k0 + lcol, &gl[r * BK]);
            glds16(wu_base + (size_t)rr * DMODEL + k0 + lcol, &ul[r * BK]);
            if (YMAT) glds16(y_base + (size_t)rr * DMODEL + k0 + lcol, &yl[r * BK]);
        }
        if (!YMAT) {
            int r = tid >> 1, half = tid & 1;
            const float4* src = (const float4*)(x + (size_t)m_t * DMODEL + k0 + half * 32);
            #pragma unroll
            for (int i = 0; i < 8; ++i) {
                float4 v = m_valid ? src[i] : (float4){0.f, 0.f, 0.f, 0.f};
                ushort4 o;
                o.x = f2bf(v.x * m_w); o.y = f2bf(v.y * m_w);
                o.z = f2bf(v.z * m_w); o.w = f2bf(v.w * m_w);
                *(ushort4*)&yl[r * BK + half * 32 + i * 4] = o;
            }
        }
        __syncthreads();
        #pragma unroll
        for (int kk = 0; kk < BK; kk += 32) {
            bf16x8 af[4], bg[4], bu[4];
            int ko = kk + (lane >> 4) * 8;
            int rsel = lane & 15;
            #pragma unroll
            for (int mi = 0; mi < 4; ++mi)
                af[mi] = *(const bf16x8*)&yl[(wm * 64 + mi * 16 + rsel) * BK + ko];
            #pragma unroll
            for (int ni = 0; ni < 4; ++ni) {
                bg[ni] = *(const bf16x8*)&gl[(wn * 64 + ni * 16 + rsel) * BK + ko];
                bu[ni] = *(const bf16x8*)&ul[(wn * 64 + ni * 16 + rsel) * BK + ko];
            }
            #pragma unroll
            for (int mi = 0; mi < 4; ++mi)
                #pragma unroll
                for (int ni = 0; ni < 4; ++ni) {
                    accg[mi][ni] = __builtin_amdgcn_mfma_f32_16x16x32_bf16(af[mi], bg[ni], accg[mi][ni], 0, 0, 0);
                    accu[mi][ni] = __builtin_amdgcn_mfma_f32_16x16x32_bf16(af[mi], bu[ni], accu[mi][ni], 0, 0, 0);
                }
        }
        __syncthreads();
    }
    // epilogue: h = silu(g)*u, column-sum over the block's 128 rows
    #pragma unroll
    for (int ni = 0; ni < 4; ++ni) {
        float s = 0.f;
        #pragma unroll
        for (int mi = 0; mi < 4; ++mi)
            #pragma unroll
            for (int i = 0; i < 4; ++i) {
                float g = accg[mi][ni][i], u = accu[mi][ni][i];
                s += (g / (1.f + __expf(-g))) * u;
            }
        s += __shfl_xor(s, 16);
        s += __shfl_xor(s, 32);
        if (lane < 16) red[wave][ni * 16 + lane] = s;
    }
    __syncthreads();
    if (tid < BN) {
        int c = tid;
        float v = red[(c >> 6)][c & 63] + red[2 + (c >> 6)][c & 63];
        atomicAdd(&hsum[(size_t)e * HDIM + n0 + c], v);
    }
}

// ---------------- 6) down-proj matvec: out[e][:] = hsum[e] @ Wd[e] ----------------
__global__ __launch_bounds__(256) void down_proj(const float* __restrict__ hsum,
                                                 const float* __restrict__ wd,
                                                 float* __restrict__ out) {
    int e = blockIdx.x;
    int d = blockIdx.y * 256 + threadIdx.x;
    __shared__ float sh[HDIM];
    for (int u = threadIdx.x; u < HDIM; u += 256) sh[u] = hsum[(size_t)e * HDIM + u];
    __syncthreads();
    const float* wp = wd + (size_t)e * HDIM * DMODEL + d;
    float acc = 0.f;
    #pragma unroll 4
    for (int h = 0; h < HDIM; h += 4) {
        float4 s4 = *(const float4*)&sh[h];
        acc += s4.x * wp[(size_t)(h + 0) * DMODEL];
        acc += s4.y * wp[(size_t)(h + 1) * DMODEL];
        acc += s4.z * wp[(size_t)(h + 2) * DMODEL];
        acc += s4.w * wp[(size_t)(h + 3) * DMODEL];
    }
    out[(size_t)e * DMODEL + d] = acc;
}

// ---------------- host ----------------
extern "C" void kernel_launch(void* const* d_in, const int* in_sizes, int n_in,
                              void* d_out, int out_size, void* d_ws, size_t ws_size,
                              hipStream_t stream) {
    const float* x     = (const float*)d_in[0];
    const float* gw    = (const float*)d_in[1];
    const float* wgate = (const float*)d_in[2];
    const float* wup   = (const float*)d_in[3];
    const float* wdown = (const float*)d_in[4];
    float* out = (float*)d_out;
    char*  ws  = (char*)d_ws;

    int*   counts = (int*)(ws + OFF_COUNTS);
    int*   nwork  = (int*)(ws + OFF_NWORK);
    float* fsum   = (float*)(ws + OFF_FSUM);
    float* psum   = (float*)(ws + OFF_PSUM);
    int4*  workv  = (int4*)(ws + OFF_WORK);
    float* hsum   = (float*)(ws + OFF_HSUM);
    int*   tok    = (int*)(ws + OFF_TOK);
    float* wgt    = (float*)(ws + OFF_WGT);
    unsigned short* wt   = (unsigned short*)(ws + OFF_WT);
    unsigned short* ybuf = (unsigned short*)(ws + OFF_Y);

    // zero output (ref output is zero outside rows 0..7 + aux) and accumulators
    hipMemsetAsync(d_out, 0, (size_t)out_size * sizeof(float), stream);
    hipMemsetAsync(d_ws, 0, OFF_ZERO_END, stream);

    wt_transpose<<<dim3(512, 8, 2), 256, 0, stream>>>(wgate, wup, wt);
    gating<<<256, 256, 0, stream>>>(x, gw, counts, fsum, psum, tok, wgt);
    build_work<<<1, 64, 0, stream>>>(counts, workv, nwork, fsum, psum,
                                     out + (size_t)T_TOK * DMODEL);

    bool fast = ws_size >= NEED_FAST;
    if (fast) {
        materialize<<<NWORK_MAX, 256, 0, stream>>>(x, tok, wgt, counts, workv, nwork, ybuf);
        moe_gemm<true><<<dim3(NWORK_MAX, HDIM / BN), 256, 0, stream>>>(
            ybuf, x, tok, wgt, wt, counts, workv, nwork, hsum);
    } else {
        moe_gemm<false><<<dim3(NWORK_MAX, HDIM / BN), 256, 0, stream>>>(
            ybuf, x, tok, wgt, wt, counts, workv, nwork, hsum);
    }

    down_proj<<<dim3(NEXP, DMODEL / 256), 256, 0, stream>>>(hsum, wdown, out);
}

// Round 2
// 526.298 us; speedup vs baseline: 1.1073x; 1.1073x over previous
//
#include <hip/hip_runtime.h>
#include <hip/hip_bf16.h>
#include <stdint.h>

// ---------------- problem constants ----------------
#define T_TOK  16384   // B*S
#define DMODEL 1024
#define NEXP   8
#define HDIM   2048
#define CAPSL  16512   // per-expert list capacity (max possible = T_TOK)

// GEMM tiling: 256x128 tile, BK=64, 8 waves (4M x 2N), double-buffered 128KB LDS
#define BM 256
#define BN 128
#define BK 64
#define NWORK_MAX 136            // sum_e ceil(N_e/256) <= 32768/256 + 8
#define YROWS_MAX (NWORK_MAX*BM)
#define LDSBUF 65536             // bytes per buffer: Y 32K + G 16K + U 16K

// ---------------- workspace layout (bytes) ----------------
#define OFF_COUNTS 0                   // int[8]
#define OFF_NWORK  64                  // int
#define OFF_FSUM   128                 // float[8]
#define OFF_PSUM   192                 // float[8]
#define OFF_WORK   256                 // int4[NWORK_MAX]
#define OFF_HSUM   8192                // float[NEXP*HDIM] = 64KB
#define OFF_ZERO_END 73728             // memset range [0, OFF_ZERO_END)
#define OFF_TOK    131072              // int[NEXP*CAPSL]
#define OFF_WGT    786432              // float[NEXP*CAPSL]
#define OFF_WT     2097152             // bf16 WgT then WuT, each [NEXP*HDIM*DMODEL]
#define WT_ELEMS   (NEXP*HDIM*DMODEL)  // 16.7M elems
#define OFF_Y      (OFF_WT + (size_t)2*WT_ELEMS*2)          // 69,206,016
#define NEED_FAST  (OFF_Y + (size_t)YROWS_MAX*DMODEL*2)     // ~140.5 MB

typedef __attribute__((ext_vector_type(4))) float f32x4;
typedef __attribute__((ext_vector_type(8))) short bf16x8;

__device__ __forceinline__ unsigned short f2bf(float f) {
    unsigned int u = __builtin_bit_cast(unsigned int, f);
    unsigned int r = (u + 0x7fffu + ((u >> 16) & 1u)) >> 16;
    return (unsigned short)r;
}

__device__ __forceinline__ void glds16(const void* g, void* l) {
    // width-16 global->LDS DMA; LDS dest is wave-uniform base + lane*16 (linear)
    __builtin_amdgcn_global_load_lds((const __attribute__((address_space(1))) void*)g,
                                     (__attribute__((address_space(3))) void*)l, 16, 0, 0);
}

// ---------------- 1) weight transpose: f32 [E][D][H] -> bf16 [E][H][D] ----------------
__global__ __launch_bounds__(256) void wt_transpose(const float* __restrict__ wg,
                                                    const float* __restrict__ wu,
                                                    unsigned short* __restrict__ wt_out) {
    int mat = blockIdx.z;
    const float* src = mat ? wu : wg;
    unsigned short* dst = wt_out + (size_t)mat * WT_ELEMS;
    int e  = blockIdx.y;
    int kt = blockIdx.x & 15;   // D/64
    int ht = blockIdx.x >> 4;   // H/64
    __shared__ unsigned short tile[64][68];
    const float* s = src + ((size_t)e * DMODEL + kt * 64) * HDIM + ht * 64;
    for (int u = threadIdx.x; u < 1024; u += 256) {
        int r = u >> 4, c = (u & 15) * 4;
        float4 v = *(const float4*)(s + (size_t)r * HDIM + c);
        tile[r][c + 0] = f2bf(v.x); tile[r][c + 1] = f2bf(v.y);
        tile[r][c + 2] = f2bf(v.z); tile[r][c + 3] = f2bf(v.w);
    }
    __syncthreads();
    unsigned short* d = dst + ((size_t)e * HDIM + ht * 64) * DMODEL + kt * 64;
    for (int u = threadIdx.x; u < 1024; u += 256) {
        int r = u >> 4, c = (u & 15) * 4;      // r: h-local row, c: k-local col
        ushort4 o;
        o.x = tile[c + 0][r]; o.y = tile[c + 1][r];
        o.z = tile[c + 2][r]; o.w = tile[c + 3][r];
        *(ushort4*)(d + (size_t)r * DMODEL + c) = o;
    }
}

// ---------------- 2) gating: logits, top-2, aux partials, compacted lists ----------------
__global__ __launch_bounds__(256) void gating(const float* __restrict__ x,
                                              const float* __restrict__ gw,
                                              int* counts, float* fsum, float* psum,
                                              int* tok_list, float* wgt_list) {
    __shared__ float gws_t[NEXP * DMODEL];  // transposed [e][k], 32KB
    __shared__ int   ch_e[64][2];
    __shared__ float ch_w[64][2];
    __shared__ float pacc[NEXP];
    __shared__ int   hist[NEXP], gbase[NEXP], cursor[NEXP];
    if (threadIdx.x < NEXP) { pacc[threadIdx.x] = 0.f; hist[threadIdx.x] = 0; cursor[threadIdx.x] = 0; }
    for (int u = threadIdx.x; u < NEXP * DMODEL; u += 256) {
        gws_t[(u & 7) * DMODEL + (u >> 3)] = gw[u];
    }
    __syncthreads();
    int wave = threadIdx.x >> 6, lane = threadIdx.x & 63;
    int tbase = blockIdx.x * 64;
    for (int it = 0; it < 16; ++it) {
        int slot = wave * 16 + it;
        int t = tbase + slot;
        float p[8] = {0, 0, 0, 0, 0, 0, 0, 0};
        #pragma unroll
        for (int j = 0; j < 16; ++j) {
            float xv = x[(size_t)t * DMODEL + j * 64 + lane];
            #pragma unroll
            for (int e2 = 0; e2 < 8; ++e2) p[e2] += xv * gws_t[e2 * DMODEL + j * 64 + lane];
        }
        #pragma unroll
        for (int off = 32; off >= 1; off >>= 1) {
            #pragma unroll
            for (int e2 = 0; e2 < 8; ++e2) p[e2] += __shfl_xor(p[e2], off);
        }
        if (lane == 0) {
            int i0 = 0; float l0 = p[0];
            #pragma unroll
            for (int e2 = 1; e2 < 8; ++e2) if (p[e2] > l0) { l0 = p[e2]; i0 = e2; }
            int i1 = -1; float l1 = -1e30f;
            #pragma unroll
            for (int e2 = 0; e2 < 8; ++e2) if (e2 != i0 && p[e2] > l1) { l1 = p[e2]; i1 = e2; }
            float a = __expf(l1 - l0);
            float w0 = 1.f / (1.f + a);
            ch_e[slot][0] = i0; ch_e[slot][1] = i1;
            ch_w[slot][0] = w0; ch_w[slot][1] = a * w0;
            atomicAdd(&hist[i0], 1); atomicAdd(&hist[i1], 1);
            float s = 0.f, ex[8];
            #pragma unroll
            for (int e2 = 0; e2 < 8; ++e2) { ex[e2] = __expf(p[e2] - l0); s += ex[e2]; }
            float inv = 1.f / s;
            #pragma unroll
            for (int e2 = 0; e2 < 8; ++e2) atomicAdd(&pacc[e2], ex[e2] * inv);
        }
    }
    __syncthreads();
    if (threadIdx.x < NEXP) {
        int h = hist[threadIdx.x];
        gbase[threadIdx.x] = atomicAdd(&counts[threadIdx.x], h);
        atomicAdd(&fsum[threadIdx.x], (float)h);
        atomicAdd(&psum[threadIdx.x], pacc[threadIdx.x]);
    }
    __syncthreads();
    if (threadIdx.x < 64) {
        int slot = threadIdx.x, t = tbase + slot;
        #pragma unroll
        for (int k2 = 0; k2 < 2; ++k2) {
            int e2 = ch_e[slot][k2];
            int pos = gbase[e2] + atomicAdd(&cursor[e2], 1);
            tok_list[e2 * CAPSL + pos] = t;
            wgt_list[e2 * CAPSL + pos] = ch_w[slot][k2];
        }
    }
}

// ---------------- 3) worklist + aux loss ----------------
__global__ void build_work(const int* counts, int4* work, int* n_work,
                           const float* fsum, const float* psum, float* out_aux) {
    if (threadIdx.x == 0 && blockIdx.x == 0) {
        int nw = 0, yb = 0;
        for (int e = 0; e < NEXP; ++e) {
            int c = counts[e];
            int nt = (c + BM - 1) / BM;
            for (int r = 0; r < nt; ++r) { work[nw] = make_int4(e, r * BM, yb, 0); yb += BM; ++nw; }
        }
        *n_work = nw;
        float aux = 0.f;
        for (int e = 0; e < NEXP; ++e)
            aux += (fsum[e] / (float)T_TOK) * (psum[e] / (float)T_TOK);
        *out_aux = aux * (float)(NEXP * NEXP);
    }
}

// ---------------- 4) materialize gathered+scaled Y as bf16 (plain layout) ----------------
__global__ __launch_bounds__(256) void materialize(const float* __restrict__ x,
                                                   const int* __restrict__ tok_list,
                                                   const float* __restrict__ wgt_list,
                                                   const int* __restrict__ counts,
                                                   const int4* __restrict__ work,
                                                   const int* __restrict__ n_work,
                                                   unsigned short* __restrict__ ybuf) {
    int w = blockIdx.x; if (w >= *n_work) return;
    int4 wi = work[w];
    int e = wi.x, row0 = wi.y, yb = wi.z;
    int cnt = counts[e];
    int rbase = blockIdx.y * 64;   // 4 y-blocks cover BM=256 rows
    for (int u = threadIdx.x; u < 64 * 256; u += 256) {   // one ushort4 per unit
        int r = rbase + (u >> 8), c = (u & 255) * 4;
        int slot = row0 + r;
        ushort4 o;
        if (slot < cnt) {
            int t = tok_list[e * CAPSL + slot];
            float wgt = wgt_list[e * CAPSL + slot];
            float4 v = *(const float4*)(x + (size_t)t * DMODEL + c);
            o.x = f2bf(v.x * wgt); o.y = f2bf(v.y * wgt);
            o.z = f2bf(v.z * wgt); o.w = f2bf(v.w * wgt);
        } else { o.x = o.y = o.z = o.w = 0; }
        *(ushort4*)(ybuf + (size_t)(yb + r) * DMODEL + c) = o;
    }
}

// ---------------- 5) fused dual-GEMM, counted-vmcnt pipeline + XOR swizzle ----------------
// LDS per buffer: Y[256][64] (32KB) | G[128][64] (16KB) | U[128][64] (16KB); x2 buffers.
// Swizzle: 16B chunk q of row r lives at physical chunk q^(r&7); applied at glds SOURCE
// address (LDS dest stays linear, rule 21) and at ds_read address.
template <bool YMAT>
__global__ __launch_bounds__(512, 2) void moe_gemm(
        const unsigned short* __restrict__ ybuf,
        const float* __restrict__ x,
        const int* __restrict__ tok_list, const float* __restrict__ wgt_list,
        const unsigned short* __restrict__ wt,   // [2][E][H][D] bf16
        const int* __restrict__ counts,
        const int4* __restrict__ work, const int* __restrict__ n_work,
        float* __restrict__ hsum) {
    int w = blockIdx.x; if (w >= *n_work) return;
    int4 wi = work[w];
    int e = wi.x, row0 = wi.y, yb = wi.z;
    int n0 = blockIdx.y * BN;
    extern __shared__ char smem[];
    __shared__ float red[8][64];
    int tid = threadIdx.x, wave = tid >> 6, lane = tid & 63;
    int wm = wave >> 1, wn = wave & 1;       // 4M x 2N wave grid
    int lrow = lane >> 3, lq = lane & 7;     // staging decomposition (8 rows x 8 chunks)
    int rsel = lane & 15, qsel = lane >> 4;  // MFMA fragment decomposition

    f32x4 accg[4][4], accu[4][4];
    #pragma unroll
    for (int mi = 0; mi < 4; ++mi)
        #pragma unroll
        for (int ni = 0; ni < 4; ++ni) {
            accg[mi][ni] = (f32x4){0.f, 0.f, 0.f, 0.f};
            accu[mi][ni] = (f32x4){0.f, 0.f, 0.f, 0.f};
        }
    const unsigned short* wg_base = wt + ((size_t)e * HDIM + n0) * DMODEL;
    const unsigned short* wu_base = wg_base + (size_t)WT_ELEMS;
    const unsigned short* y_base  = ybuf + (size_t)yb * DMODEL;

    // fallback (reg-staged Y) per-thread token info
    int m_t = 0; float m_w = 0.f; bool m_valid = false;
    int frow = tid >> 1, fhalf = tid & 1;
    if (!YMAT) {
        int slot = row0 + frow;
        int cnt = counts[e];
        m_valid = slot < cnt;
        if (m_valid) { m_t = tok_list[e * CAPSL + slot]; m_w = wgt_list[e * CAPSL + slot]; }
    }

    auto stage = [&](int buf, int k0) {
        char* sb = smem + buf * LDSBUF;
        if constexpr (YMAT) {
            #pragma unroll
            for (int c = 0; c < 4; ++c) {
                int rb = wave * 32 + c * 8;   // wave-uniform LDS row base
                glds16(y_base + (size_t)(rb + lrow) * DMODEL + k0 + ((lq ^ lrow) * 8),
                       sb + rb * 128);
            }
        }
        #pragma unroll
        for (int c = 0; c < 2; ++c) {
            int rb = wave * 16 + c * 8;
            glds16(wg_base + (size_t)(rb + lrow) * DMODEL + k0 + ((lq ^ lrow) * 8),
                   sb + 32768 + rb * 128);
            glds16(wu_base + (size_t)(rb + lrow) * DMODEL + k0 + ((lq ^ lrow) * 8),
                   sb + 49152 + rb * 128);
        }
    };

    stage(0, 0);
    int cur = 0;
    for (int t = 0; t < DMODEL / BK; ++t) {
        int k0 = t * BK;
        if (t < DMODEL / BK - 1) {
            stage(cur ^ 1, k0 + BK);               // prefetch next tile (8 or 4 glds)
            if constexpr (YMAT) asm volatile("s_waitcnt vmcnt(8)" ::: "memory");
            else                asm volatile("s_waitcnt vmcnt(0)" ::: "memory");
        } else {
            asm volatile("s_waitcnt vmcnt(0)" ::: "memory");
        }
        __builtin_amdgcn_s_barrier();
        __builtin_amdgcn_sched_barrier(0);
        if constexpr (!YMAT) {
            // reg-stage Y with swizzled ds_write
            unsigned short* yw = (unsigned short*)(smem + cur * LDSBUF);
            const float4* src = (const float4*)(x + (size_t)m_t * DMODEL + k0 + fhalf * 32);
            #pragma unroll
            for (int j = 0; j < 4; ++j) {
                float4 v0 = m_valid ? src[2 * j]     : (float4){0.f, 0.f, 0.f, 0.f};
                float4 v1 = m_valid ? src[2 * j + 1] : (float4){0.f, 0.f, 0.f, 0.f};
                bf16x8 o;
                o[0] = f2bf(v0.x * m_w); o[1] = f2bf(v0.y * m_w);
                o[2] = f2bf(v0.z * m_w); o[3] = f2bf(v0.w * m_w);
                o[4] = f2bf(v1.x * m_w); o[5] = f2bf(v1.y * m_w);
                o[6] = f2bf(v1.z * m_w); o[7] = f2bf(v1.w * m_w);
                int q = fhalf * 4 + j;
                *(bf16x8*)&yw[frow * BK + ((q ^ (frow & 7)) * 8)] = o;
            }
            asm volatile("s_waitcnt lgkmcnt(0)" ::: "memory");
            __builtin_amdgcn_s_barrier();
            __builtin_amdgcn_sched_barrier(0);
        }
        const unsigned short* yp = (const unsigned short*)(smem + cur * LDSBUF);
        const unsigned short* gp = yp + 16384;
        const unsigned short* up = yp + 24576;
        #pragma unroll
        for (int kk = 0; kk < 2; ++kk) {
            int qb = kk * 4 + qsel;               // logical 16B chunk index (0..7)
            bf16x8 af[4], bg[4], bu[4];
            #pragma unroll
            for (int mi = 0; mi < 4; ++mi) {
                int r = wm * 64 + mi * 16 + rsel;
                af[mi] = *(const bf16x8*)&yp[r * BK + ((qb ^ (rsel & 7)) * 8)];
            }
            #pragma unroll
            for (int ni = 0; ni < 4; ++ni) {
                int r = wn * 64 + ni * 16 + rsel;
                int off = r * BK + ((qb ^ (rsel & 7)) * 8);
                bg[ni] = *(const bf16x8*)&gp[off];
                bu[ni] = *(const bf16x8*)&up[off];
            }
            __builtin_amdgcn_s_setprio(1);
            #pragma unroll
            for (int mi = 0; mi < 4; ++mi)
                #pragma unroll
                for (int ni = 0; ni < 4; ++ni) {
                    accg[mi][ni] = __builtin_amdgcn_mfma_f32_16x16x32_bf16(af[mi], bg[ni], accg[mi][ni], 0, 0, 0);
                    accu[mi][ni] = __builtin_amdgcn_mfma_f32_16x16x32_bf16(af[mi], bu[ni], accu[mi][ni], 0, 0, 0);
                }
            __builtin_amdgcn_s_setprio(0);
        }
        __builtin_amdgcn_sched_barrier(0);
        __builtin_amdgcn_s_barrier();
        cur ^= 1;
    }
    // epilogue: h = silu(g)*u, column-sum over the block's 256 rows
    #pragma unroll
    for (int ni = 0; ni < 4; ++ni) {
        float s = 0.f;
        #pragma unroll
        for (int mi = 0; mi < 4; ++mi)
            #pragma unroll
            for (int i = 0; i < 4; ++i) {
                float g = accg[mi][ni][i], u = accu[mi][ni][i];
                s += (g / (1.f + __expf(-g))) * u;
            }
        s += __shfl_xor(s, 16);
        s += __shfl_xor(s, 32);
        if (lane < 16) red[wave][ni * 16 + lane] = s;
    }
    __syncthreads();
    if (tid < BN) {
        int wnc = tid >> 6, idx = tid & 63;
        float v = red[wnc][idx] + red[2 + wnc][idx] + red[4 + wnc][idx] + red[6 + wnc][idx];
        atomicAdd(&hsum[(size_t)e * HDIM + n0 + tid], v);
    }
}

// ---------------- 6) down-proj matvec: out[e][:] = hsum[e] @ Wd[e] ----------------
__global__ __launch_bounds__(256) void down_proj(const float* __restrict__ hsum,
                                                 const float* __restrict__ wd,
                                                 float* __restrict__ out) {
    int e = blockIdx.x;
    int d = blockIdx.y * 256 + threadIdx.x;
    __shared__ float sh[HDIM];
    for (int u = threadIdx.x; u < HDIM; u += 256) sh[u] = hsum[(size_t)e * HDIM + u];
    __syncthreads();
    const float* wp = wd + (size_t)e * HDIM * DMODEL + d;
    float acc = 0.f;
    #pragma unroll 4
    for (int h = 0; h < HDIM; h += 4) {
        float4 s4 = *(const float4*)&sh[h];
        acc += s4.x * wp[(size_t)(h + 0) * DMODEL];
        acc += s4.y * wp[(size_t)(h + 1) * DMODEL];
        acc += s4.z * wp[(size_t)(h + 2) * DMODEL];
        acc += s4.w * wp[(size_t)(h + 3) * DMODEL];
    }
    out[(size_t)e * DMODEL + d] = acc;
}

// ---------------- host ----------------
extern "C" void kernel_launch(void* const* d_in, const int* in_sizes, int n_in,
                              void* d_out, int out_size, void* d_ws, size_t ws_size,
                              hipStream_t stream) {
    const float* x     = (const float*)d_in[0];
    const float* gw    = (const float*)d_in[1];
    const float* wgate = (const float*)d_in[2];
    const float* wup   = (const float*)d_in[3];
    const float* wdown = (const float*)d_in[4];
    float* out = (float*)d_out;
    char*  ws  = (char*)d_ws;

    int*   counts = (int*)(ws + OFF_COUNTS);
    int*   nwork  = (int*)(ws + OFF_NWORK);
    float* fsum   = (float*)(ws + OFF_FSUM);
    float* psum   = (float*)(ws + OFF_PSUM);
    int4*  workv  = (int4*)(ws + OFF_WORK);
    float* hsum   = (float*)(ws + OFF_HSUM);
    int*   tok    = (int*)(ws + OFF_TOK);
    float* wgt    = (float*)(ws + OFF_WGT);
    unsigned short* wt   = (unsigned short*)(ws + OFF_WT);
    unsigned short* ybuf = (unsigned short*)(ws + OFF_Y);

    // allow 128KB dynamic LDS (idempotent, deterministic)
    hipFuncSetAttribute(reinterpret_cast<const void*>(moe_gemm<true>),
                        hipFuncAttributeMaxDynamicSharedMemorySize, 2 * LDSBUF);
    hipFuncSetAttribute(reinterpret_cast<const void*>(moe_gemm<false>),
                        hipFuncAttributeMaxDynamicSharedMemorySize, 2 * LDSBUF);

    // zero output (ref output is zero outside rows 0..7 + aux) and accumulators
    hipMemsetAsync(d_out, 0, (size_t)out_size * sizeof(float), stream);
    hipMemsetAsync(d_ws, 0, OFF_ZERO_END, stream);

    wt_transpose<<<dim3(512, 8, 2), 256, 0, stream>>>(wgate, wup, wt);
    gating<<<256, 256, 0, stream>>>(x, gw, counts, fsum, psum, tok, wgt);
    build_work<<<1, 64, 0, stream>>>(counts, workv, nwork, fsum, psum,
                                     out + (size_t)T_TOK * DMODEL);

    bool fast = ws_size >= NEED_FAST;
    if (fast) {
        materialize<<<dim3(NWORK_MAX, 4), 256, 0, stream>>>(x, tok, wgt, counts, workv, nwork, ybuf);
        moe_gemm<true><<<dim3(NWORK_MAX, HDIM / BN), 512, 2 * LDSBUF, stream>>>(
            ybuf, x, tok, wgt, wt, counts, workv, nwork, hsum);
    } else {
        moe_gemm<false><<<dim3(NWORK_MAX, HDIM / BN), 512, 2 * LDSBUF, stream>>>(
            ybuf, x, tok, wgt, wt, counts, workv, nwork, hsum);
    }

    down_proj<<<dim3(NEXP, DMODEL / 256), 256, 0, stream>>>(hsum, wdown, out);
}

// Round 3
// 524.009 us; speedup vs baseline: 1.1122x; 1.0044x over previous
//
#include <hip/hip_runtime.h>
#include <hip/hip_bf16.h>
#include <stdint.h>

// ---------------- problem constants ----------------
#define T_TOK  16384   // B*S
#define DMODEL 1024
#define NEXP   8
#define HDIM   2048
#define CAPSL  16512   // per-expert list capacity

// GEMM tiling: 256x128 tile, 32 K-slices of 32, 4 LDS slots, 8 waves (4M x 2N)
#define BM 256
#define BN 128
#define NWORK_MAX 136            // sum_e ceil(N_e/256) <= 32768/256 + 8
#define YROWS_MAX (NWORK_MAX*BM)
#define SLOT_BYTES 32768         // Y 16K + G 8K + U 8K
#define GRID_GEMM (NWORK_MAX * (HDIM / BN))   // 2176 (divisible by 8)

// ---------------- workspace layout (bytes) ----------------
#define OFF_COUNTS 0                   // int[8]
#define OFF_NWORK  64                  // int
#define OFF_FSUM   128                 // float[8]
#define OFF_PSUM   192                 // float[8]
#define OFF_WORK   256                 // int4[NWORK_MAX]
#define OFF_HSUM   8192                // float[NEXP*HDIM] = 64KB
#define OFF_ZERO_END 73728             // memset range [0, OFF_ZERO_END)
#define OFF_TOK    131072              // int[NEXP*CAPSL]
#define OFF_WGT    786432              // float[NEXP*CAPSL]
#define OFF_WT     2097152             // bf16 WgT then WuT, each [NEXP*HDIM*DMODEL]
#define WT_ELEMS   (NEXP*HDIM*DMODEL)  // 16.7M elems
#define OFF_Y      (OFF_WT + (size_t)2*WT_ELEMS*2)          // 69,206,016
#define NEED_FAST  (OFF_Y + (size_t)YROWS_MAX*DMODEL*2)     // ~140.5 MB

typedef __attribute__((ext_vector_type(4))) float f32x4;
typedef __attribute__((ext_vector_type(8))) short bf16x8;

__device__ __forceinline__ unsigned short f2bf(float f) {
    unsigned int u = __builtin_bit_cast(unsigned int, f);
    unsigned int r = (u + 0x7fffu + ((u >> 16) & 1u)) >> 16;
    return (unsigned short)r;
}

__device__ __forceinline__ void glds16(const void* g, void* l) {
    // width-16 global->LDS DMA; LDS dest is wave-uniform base + lane*16 (linear)
    __builtin_amdgcn_global_load_lds((const __attribute__((address_space(1))) void*)g,
                                     (__attribute__((address_space(3))) void*)l, 16, 0, 0);
}

// ---------------- 1) weight transpose: f32 [E][D][H] -> bf16 [E][H][D] ----------------
__global__ __launch_bounds__(256) void wt_transpose(const float* __restrict__ wg,
                                                    const float* __restrict__ wu,
                                                    unsigned short* __restrict__ wt_out) {
    int mat = blockIdx.z;
    const float* src = mat ? wu : wg;
    unsigned short* dst = wt_out + (size_t)mat * WT_ELEMS;
    int e  = blockIdx.y;
    int kt = blockIdx.x & 15;   // D/64
    int ht = blockIdx.x >> 4;   // H/64
    __shared__ unsigned short tile[64][68];
    const float* s = src + ((size_t)e * DMODEL + kt * 64) * HDIM + ht * 64;
    for (int u = threadIdx.x; u < 1024; u += 256) {
        int r = u >> 4, c = (u & 15) * 4;
        float4 v = *(const float4*)(s + (size_t)r * HDIM + c);
        tile[r][c + 0] = f2bf(v.x); tile[r][c + 1] = f2bf(v.y);
        tile[r][c + 2] = f2bf(v.z); tile[r][c + 3] = f2bf(v.w);
    }
    __syncthreads();
    unsigned short* d = dst + ((size_t)e * HDIM + ht * 64) * DMODEL + kt * 64;
    for (int u = threadIdx.x; u < 1024; u += 256) {
        int r = u >> 4, c = (u & 15) * 4;
        ushort4 o;
        o.x = tile[c + 0][r]; o.y = tile[c + 1][r];
        o.z = tile[c + 2][r]; o.w = tile[c + 3][r];
        *(ushort4*)(d + (size_t)r * DMODEL + c) = o;
    }
}

// ---------------- 2) gating ----------------
__global__ __launch_bounds__(256) void gating(const float* __restrict__ x,
                                              const float* __restrict__ gw,
                                              int* counts, float* fsum, float* psum,
                                              int* tok_list, float* wgt_list) {
    __shared__ float gws_t[NEXP * DMODEL];
    __shared__ int   ch_e[64][2];
    __shared__ float ch_w[64][2];
    __shared__ float pacc[NEXP];
    __shared__ int   hist[NEXP], gbase[NEXP], cursor[NEXP];
    if (threadIdx.x < NEXP) { pacc[threadIdx.x] = 0.f; hist[threadIdx.x] = 0; cursor[threadIdx.x] = 0; }
    for (int u = threadIdx.x; u < NEXP * DMODEL; u += 256) {
        gws_t[(u & 7) * DMODEL + (u >> 3)] = gw[u];
    }
    __syncthreads();
    int wave = threadIdx.x >> 6, lane = threadIdx.x & 63;
    int tbase = blockIdx.x * 64;
    for (int it = 0; it < 16; ++it) {
        int slot = wave * 16 + it;
        int t = tbase + slot;
        float p[8] = {0, 0, 0, 0, 0, 0, 0, 0};
        #pragma unroll
        for (int j = 0; j < 16; ++j) {
            float xv = x[(size_t)t * DMODEL + j * 64 + lane];
            #pragma unroll
            for (int e2 = 0; e2 < 8; ++e2) p[e2] += xv * gws_t[e2 * DMODEL + j * 64 + lane];
        }
        #pragma unroll
        for (int off = 32; off >= 1; off >>= 1) {
            #pragma unroll
            for (int e2 = 0; e2 < 8; ++e2) p[e2] += __shfl_xor(p[e2], off);
        }
        if (lane == 0) {
            int i0 = 0; float l0 = p[0];
            #pragma unroll
            for (int e2 = 1; e2 < 8; ++e2) if (p[e2] > l0) { l0 = p[e2]; i0 = e2; }
            int i1 = -1; float l1 = -1e30f;
            #pragma unroll
            for (int e2 = 0; e2 < 8; ++e2) if (e2 != i0 && p[e2] > l1) { l1 = p[e2]; i1 = e2; }
            float a = __expf(l1 - l0);
            float w0 = 1.f / (1.f + a);
            ch_e[slot][0] = i0; ch_e[slot][1] = i1;
            ch_w[slot][0] = w0; ch_w[slot][1] = a * w0;
            atomicAdd(&hist[i0], 1); atomicAdd(&hist[i1], 1);
            float s = 0.f, ex[8];
            #pragma unroll
            for (int e2 = 0; e2 < 8; ++e2) { ex[e2] = __expf(p[e2] - l0); s += ex[e2]; }
            float inv = 1.f / s;
            #pragma unroll
            for (int e2 = 0; e2 < 8; ++e2) atomicAdd(&pacc[e2], ex[e2] * inv);
        }
    }
    __syncthreads();
    if (threadIdx.x < NEXP) {
        int h = hist[threadIdx.x];
        gbase[threadIdx.x] = atomicAdd(&counts[threadIdx.x], h);
        atomicAdd(&fsum[threadIdx.x], (float)h);
        atomicAdd(&psum[threadIdx.x], pacc[threadIdx.x]);
    }
    __syncthreads();
    if (threadIdx.x < 64) {
        int slot = threadIdx.x, t = tbase + slot;
        #pragma unroll
        for (int k2 = 0; k2 < 2; ++k2) {
            int e2 = ch_e[slot][k2];
            int pos = gbase[e2] + atomicAdd(&cursor[e2], 1);
            tok_list[e2 * CAPSL + pos] = t;
            wgt_list[e2 * CAPSL + pos] = ch_w[slot][k2];
        }
    }
}

// ---------------- 3) worklist + aux loss ----------------
__global__ void build_work(const int* counts, int4* work, int* n_work,
                           const float* fsum, const float* psum, float* out_aux) {
    if (threadIdx.x == 0 && blockIdx.x == 0) {
        int nw = 0, yb = 0;
        for (int e = 0; e < NEXP; ++e) {
            int c = counts[e];
            int nt = (c + BM - 1) / BM;
            for (int r = 0; r < nt; ++r) { work[nw] = make_int4(e, r * BM, yb, 0); yb += BM; ++nw; }
        }
        *n_work = nw;
        float aux = 0.f;
        for (int e = 0; e < NEXP; ++e)
            aux += (fsum[e] / (float)T_TOK) * (psum[e] / (float)T_TOK);
        *out_aux = aux * (float)(NEXP * NEXP);
    }
}

// ---------------- 4) materialize gathered+scaled Y as bf16 ----------------
__global__ __launch_bounds__(256) void materialize(const float* __restrict__ x,
                                                   const int* __restrict__ tok_list,
                                                   const float* __restrict__ wgt_list,
                                                   const int* __restrict__ counts,
                                                   const int4* __restrict__ work,
                                                   const int* __restrict__ n_work,
                                                   unsigned short* __restrict__ ybuf) {
    int w = blockIdx.x; if (w >= *n_work) return;
    int4 wi = work[w];
    int e = wi.x, row0 = wi.y, yb = wi.z;
    int cnt = counts[e];
    int rbase = blockIdx.y * 64;
    for (int u = threadIdx.x; u < 64 * 256; u += 256) {
        int r = rbase + (u >> 8), c = (u & 255) * 4;
        int slot = row0 + r;
        ushort4 o;
        if (slot < cnt) {
            int t = tok_list[e * CAPSL + slot];
            float wgt = wgt_list[e * CAPSL + slot];
            float4 v = *(const float4*)(x + (size_t)t * DMODEL + c);
            o.x = f2bf(v.x * wgt); o.y = f2bf(v.y * wgt);
            o.z = f2bf(v.z * wgt); o.w = f2bf(v.w * wgt);
        } else { o.x = o.y = o.z = o.w = 0; }
        *(ushort4*)(ybuf + (size_t)(yb + r) * DMODEL + c) = o;
    }
}

// ---------------- 5) fused dual-GEMM: 4-slot deep pipeline (T3+T4+T2+T5+T1) ----------------
// K split into 32 slices of 32. LDS slot (32KB) = Y[256 rows] | G[128] | U[128], rows
// pair-folded: super-row sr=r>>1 is 128B = 8 chunks of 16B; logical (r,q) at chunk
// ((r&1)*4+q) ^ (sr&7). glds16 fills linearly; source address pre-swizzled (rule 21).
// Steady state: computing slice h; h+1,h+2 landed/in-flight; h+3 issuing -> vmcnt(8).
#define SLICE(h_, slot_, DO_STAGE, VM_) do {                                           \
    const char* sp = smem + (slot_) * SLOT_BYTES;                                      \
    bf16x8 af[4], bg[4], bu[4];                                                        \
    _Pragma("unroll")                                                                  \
    for (int mi = 0; mi < 4; ++mi) af[mi] = *(const bf16x8*)(sp + ay[mi]);             \
    _Pragma("unroll")                                                                  \
    for (int ni = 0; ni < 4; ++ni) {                                                   \
        bg[ni] = *(const bf16x8*)(sp + 16384 + ab[ni]);                                \
        bu[ni] = *(const bf16x8*)(sp + 24576 + ab[ni]);                                \
    }                                                                                  \
    if (DO_STAGE) stage((h_) + 3, ((slot_) + 3) & 3);                                  \
    asm volatile("s_waitcnt lgkmcnt(0)" ::: "memory");                                 \
    __builtin_amdgcn_sched_barrier(0);                                                 \
    __builtin_amdgcn_s_setprio(1);                                                     \
    _Pragma("unroll")                                                                  \
    for (int mi = 0; mi < 4; ++mi) {                                                   \
        _Pragma("unroll")                                                              \
        for (int ni = 0; ni < 4; ++ni) {                                               \
            accg[mi][ni] = __builtin_amdgcn_mfma_f32_16x16x32_bf16(af[mi], bg[ni], accg[mi][ni], 0, 0, 0); \
            accu[mi][ni] = __builtin_amdgcn_mfma_f32_16x16x32_bf16(af[mi], bu[ni], accu[mi][ni], 0, 0, 0); \
        }                                                                              \
    }                                                                                  \
    __builtin_amdgcn_s_setprio(0);                                                     \
    __builtin_amdgcn_sched_barrier(0);                                                 \
    if ((VM_) == 8)      asm volatile("s_waitcnt vmcnt(8)" ::: "memory");              \
    else if ((VM_) == 4) asm volatile("s_waitcnt vmcnt(4)" ::: "memory");              \
    else if ((VM_) == 0) asm volatile("s_waitcnt vmcnt(0)" ::: "memory");              \
    if ((VM_) >= 0) __builtin_amdgcn_s_barrier();                                      \
} while (0)

__global__ __launch_bounds__(512, 2) void moe_gemm_fast(
        const unsigned short* __restrict__ ybuf,
        const unsigned short* __restrict__ wt,   // [2][E][H][D] bf16
        const int4* __restrict__ work, const int* __restrict__ n_work,
        float* __restrict__ hsum) {
    extern __shared__ char smem[];
    __shared__ float red[8][64];
    // T1: bijective XCD swizzle (nwg=2176, nwg%8==0): each XCD gets 272 contiguous
    // swz ids = 2 full n0-slices -> weight tiles stay hot in its L2.
    int bid = blockIdx.x;
    int swz = (bid & 7) * (GRID_GEMM / 8) + (bid >> 3);
    int nblk = swz / NWORK_MAX;
    int w = swz - nblk * NWORK_MAX;
    if (w >= *n_work) return;
    int4 wi = work[w];
    int e = wi.x, yb = wi.z;
    int n0 = nblk * BN;
    int tid = threadIdx.x, wave = tid >> 6, lane = tid & 63;
    int wm = wave >> 1, wn = wave & 1;       // 4M x 2N wave grid; per-wave out 64x64 dual

    const unsigned short* wg_base = wt + ((size_t)e * HDIM + n0) * DMODEL;
    const unsigned short* wu_base = wg_base + (size_t)WT_ELEMS;
    const unsigned short* y_base  = ybuf + (size_t)yb * DMODEL;

    // staging setup: wave -> region (waves 0-3: Y, 4-5: G, 6-7: U), 4 glds16/wave/slice
    const unsigned short* gsrc; int roff, ul0;
    if (wave < 4)      { gsrc = y_base;  roff = 0;     ul0 = wave * 4; }
    else if (wave < 6) { gsrc = wg_base; roff = 16384; ul0 = (wave - 4) * 4; }
    else               { gsrc = wu_base; roff = 24576; ul0 = (wave - 6) * 4; }
    int c_  = (lane & 7) ^ (lane >> 3);          // pre-swizzled logical chunk
    int rl  = ((lane >> 3) << 1) | (c_ >> 2);    // logical row within 16-row unit
    int kq  = (c_ & 3) * 8;                      // k-offset (elems)
    size_t srcoff[4]; int dstoff[4];
    #pragma unroll
    for (int i = 0; i < 4; ++i) {
        srcoff[i] = (size_t)((ul0 + i) * 16 + rl) * DMODEL + kq;
        dstoff[i] = roff + (ul0 + i) * 1024;
    }
    auto stage = [&](int h, int slot) {
        char* sb = smem + slot * SLOT_BYTES;
        int k0 = h * 32;
        #pragma unroll
        for (int i = 0; i < 4; ++i)
            glds16(gsrc + srcoff[i] + k0, sb + dstoff[i]);
    };

    // fragment read offsets (swizzled): row R, chunk qsel -> sr*128 + ((c^(sr&7))*16)
    int rsel = lane & 15, qsel = lane >> 4;
    int rh = rsel >> 1, rp = (rsel & 1) * 4;
    int xorq = ((rp + qsel) ^ rh) * 16;
    int ay[4], ab[4];
    #pragma unroll
    for (int i = 0; i < 4; ++i) {
        ay[i] = (wm * 32 + i * 8 + rh) * 128 + xorq;
        ab[i] = (wn * 32 + i * 8 + rh) * 128 + xorq;
    }

    f32x4 accg[4][4], accu[4][4];
    #pragma unroll
    for (int mi = 0; mi < 4; ++mi)
        #pragma unroll
        for (int ni = 0; ni < 4; ++ni) {
            accg[mi][ni] = (f32x4){0.f, 0.f, 0.f, 0.f};
            accu[mi][ni] = (f32x4){0.f, 0.f, 0.f, 0.f};
        }

    // prologue: fill 3 slots, wait slice 0 (12 outstanding -> vmcnt(8) waits oldest 4)
    stage(0, 0); stage(1, 1); stage(2, 2);
    asm volatile("s_waitcnt vmcnt(8)" ::: "memory");
    __builtin_amdgcn_s_barrier();

    #pragma unroll 1
    for (int g = 0; g < 7; ++g) {           // slices 0..27
        int h = g * 4;
        SLICE(h + 0, 0, true, 8);
        SLICE(h + 1, 1, true, 8);
        SLICE(h + 2, 2, true, 8);
        SLICE(h + 3, 3, true, 8);
    }
    SLICE(28, 0, true, 8);                  // stages slice 31
    SLICE(29, 1, false, 4);
    SLICE(30, 2, false, 0);
    SLICE(31, 3, false, -1);

    // epilogue: h = silu(g)*u, column-sum over the block's 256 rows
    #pragma unroll
    for (int ni = 0; ni < 4; ++ni) {
        float s = 0.f;
        #pragma unroll
        for (int mi = 0; mi < 4; ++mi)
            #pragma unroll
            for (int i = 0; i < 4; ++i) {
                float gv = accg[mi][ni][i], uv = accu[mi][ni][i];
                s += (gv / (1.f + __expf(-gv))) * uv;
            }
        s += __shfl_xor(s, 16);
        s += __shfl_xor(s, 32);
        if (lane < 16) red[wave][ni * 16 + lane] = s;
    }
    __syncthreads();
    if (tid < BN) {
        int wnc = tid >> 6, idx = tid & 63;
        float v = red[wnc][idx] + red[2 + wnc][idx] + red[4 + wnc][idx] + red[6 + wnc][idx];
        atomicAdd(&hsum[(size_t)e * HDIM + n0 + tid], v);
    }
}

// ---------------- 5b) fallback GEMM (ws too small for ybuf): reg-staged from x ----------------
#define SBK 64
#define SLBUF 65536
__global__ __launch_bounds__(512, 2) void moe_gemm_slow(
        const float* __restrict__ x,
        const int* __restrict__ tok_list, const float* __restrict__ wgt_list,
        const unsigned short* __restrict__ wt,
        const int* __restrict__ counts,
        const int4* __restrict__ work, const int* __restrict__ n_work,
        float* __restrict__ hsum) {
    int w = blockIdx.x; if (w >= *n_work) return;
    int4 wi = work[w];
    int e = wi.x, row0 = wi.y;
    int n0 = blockIdx.y * BN;
    extern __shared__ char smem[];
    __shared__ float red[8][64];
    int tid = threadIdx.x, wave = tid >> 6, lane = tid & 63;
    int wm = wave >> 1, wn = wave & 1;
    int lrow = lane >> 3, lq = lane & 7;
    int rsel = lane & 15, qsel = lane >> 4;
    f32x4 accg[4][4], accu[4][4];
    #pragma unroll
    for (int mi = 0; mi < 4; ++mi)
        #pragma unroll
        for (int ni = 0; ni < 4; ++ni) {
            accg[mi][ni] = (f32x4){0.f, 0.f, 0.f, 0.f};
            accu[mi][ni] = (f32x4){0.f, 0.f, 0.f, 0.f};
        }
    const unsigned short* wg_base = wt + ((size_t)e * HDIM + n0) * DMODEL;
    const unsigned short* wu_base = wg_base + (size_t)WT_ELEMS;
    int m_t = 0; float m_w = 0.f; bool m_valid = false;
    int frow = tid >> 1, fhalf = tid & 1;
    {
        int slot = row0 + frow;
        int cnt = counts[e];
        m_valid = slot < cnt;
        if (m_valid) { m_t = tok_list[e * CAPSL + slot]; m_w = wgt_list[e * CAPSL + slot]; }
    }
    auto stage = [&](int buf, int k0) {
        char* sb = smem + buf * SLBUF;
        #pragma unroll
        for (int c = 0; c < 2; ++c) {
            int rb = wave * 16 + c * 8;
            glds16(wg_base + (size_t)(rb + lrow) * DMODEL + k0 + ((lq ^ lrow) * 8),
                   sb + 32768 + rb * 128);
            glds16(wu_base + (size_t)(rb + lrow) * DMODEL + k0 + ((lq ^ lrow) * 8),
                   sb + 49152 + rb * 128);
        }
    };
    stage(0, 0);
    int cur = 0;
    for (int t = 0; t < DMODEL / SBK; ++t) {
        int k0 = t * SBK;
        if (t < DMODEL / SBK - 1) stage(cur ^ 1, k0 + SBK);
        asm volatile("s_waitcnt vmcnt(0)" ::: "memory");
        __builtin_amdgcn_s_barrier();
        __builtin_amdgcn_sched_barrier(0);
        {
            unsigned short* yw = (unsigned short*)(smem + cur * SLBUF);
            const float4* src = (const float4*)(x + (size_t)m_t * DMODEL + k0 + fhalf * 32);
            #pragma unroll
            for (int j = 0; j < 4; ++j) {
                float4 v0 = m_valid ? src[2 * j]     : (float4){0.f, 0.f, 0.f, 0.f};
                float4 v1 = m_valid ? src[2 * j + 1] : (float4){0.f, 0.f, 0.f, 0.f};
                bf16x8 o;
                o[0] = f2bf(v0.x * m_w); o[1] = f2bf(v0.y * m_w);
                o[2] = f2bf(v0.z * m_w); o[3] = f2bf(v0.w * m_w);
                o[4] = f2bf(v1.x * m_w); o[5] = f2bf(v1.y * m_w);
                o[6] = f2bf(v1.z * m_w); o[7] = f2bf(v1.w * m_w);
                int q = fhalf * 4 + j;
                *(bf16x8*)&yw[frow * SBK + ((q ^ (frow & 7)) * 8)] = o;
            }
            asm volatile("s_waitcnt lgkmcnt(0)" ::: "memory");
            __builtin_amdgcn_s_barrier();
            __builtin_amdgcn_sched_barrier(0);
        }
        const unsigned short* yp = (const unsigned short*)(smem + cur * SLBUF);
        const unsigned short* gp = yp + 16384;
        const unsigned short* up = yp + 24576;
        #pragma unroll
        for (int kk = 0; kk < 2; ++kk) {
            int qb = kk * 4 + qsel;
            bf16x8 af[4], bg[4], bu[4];
            #pragma unroll
            for (int mi = 0; mi < 4; ++mi) {
                int r = wm * 64 + mi * 16 + rsel;
                af[mi] = *(const bf16x8*)&yp[r * SBK + ((qb ^ (rsel & 7)) * 8)];
            }
            #pragma unroll
            for (int ni = 0; ni < 4; ++ni) {
                int r = wn * 64 + ni * 16 + rsel;
                int off = r * SBK + ((qb ^ (rsel & 7)) * 8);
                bg[ni] = *(const bf16x8*)&gp[off];
                bu[ni] = *(const bf16x8*)&up[off];
            }
            __builtin_amdgcn_s_setprio(1);
            #pragma unroll
            for (int mi = 0; mi < 4; ++mi)
                #pragma unroll
                for (int ni = 0; ni < 4; ++ni) {
                    accg[mi][ni] = __builtin_amdgcn_mfma_f32_16x16x32_bf16(af[mi], bg[ni], accg[mi][ni], 0, 0, 0);
                    accu[mi][ni] = __builtin_amdgcn_mfma_f32_16x16x32_bf16(af[mi], bu[ni], accu[mi][ni], 0, 0, 0);
                }
            __builtin_amdgcn_s_setprio(0);
        }
        __builtin_amdgcn_sched_barrier(0);
        __builtin_amdgcn_s_barrier();
        cur ^= 1;
    }
    #pragma unroll
    for (int ni = 0; ni < 4; ++ni) {
        float s = 0.f;
        #pragma unroll
        for (int mi = 0; mi < 4; ++mi)
            #pragma unroll
            for (int i = 0; i < 4; ++i) {
                float gv = accg[mi][ni][i], uv = accu[mi][ni][i];
                s += (gv / (1.f + __expf(-gv))) * uv;
            }
        s += __shfl_xor(s, 16);
        s += __shfl_xor(s, 32);
        if (lane < 16) red[wave][ni * 16 + lane] = s;
    }
    __syncthreads();
    if (tid < BN) {
        int wnc = tid >> 6, idx = tid & 63;
        float v = red[wnc][idx] + red[2 + wnc][idx] + red[4 + wnc][idx] + red[6 + wnc][idx];
        atomicAdd(&hsum[(size_t)e * HDIM + n0 + tid], v);
    }
}

// ---------------- 6) down-proj matvec: out[e][:] = hsum[e] @ Wd[e] ----------------
__global__ __launch_bounds__(256) void down_proj(const float* __restrict__ hsum,
                                                 const float* __restrict__ wd,
                                                 float* __restrict__ out) {
    int e = blockIdx.x;
    int d = blockIdx.y * 256 + threadIdx.x;
    __shared__ float sh[HDIM];
    for (int u = threadIdx.x; u < HDIM; u += 256) sh[u] = hsum[(size_t)e * HDIM + u];
    __syncthreads();
    const float* wp = wd + (size_t)e * HDIM * DMODEL + d;
    float acc = 0.f;
    #pragma unroll 4
    for (int h = 0; h < HDIM; h += 4) {
        float4 s4 = *(const float4*)&sh[h];
        acc += s4.x * wp[(size_t)(h + 0) * DMODEL];
        acc += s4.y * wp[(size_t)(h + 1) * DMODEL];
        acc += s4.z * wp[(size_t)(h + 2) * DMODEL];
        acc += s4.w * wp[(size_t)(h + 3) * DMODEL];
    }
    out[(size_t)e * DMODEL + d] = acc;
}

// ---------------- host ----------------
extern "C" void kernel_launch(void* const* d_in, const int* in_sizes, int n_in,
                              void* d_out, int out_size, void* d_ws, size_t ws_size,
                              hipStream_t stream) {
    const float* x     = (const float*)d_in[0];
    const float* gw    = (const float*)d_in[1];
    const float* wgate = (const float*)d_in[2];
    const float* wup   = (const float*)d_in[3];
    const float* wdown = (const float*)d_in[4];
    float* out = (float*)d_out;
    char*  ws  = (char*)d_ws;

    int*   counts = (int*)(ws + OFF_COUNTS);
    int*   nwork  = (int*)(ws + OFF_NWORK);
    float* fsum   = (float*)(ws + OFF_FSUM);
    float* psum   = (float*)(ws + OFF_PSUM);
    int4*  workv  = (int4*)(ws + OFF_WORK);
    float* hsum   = (float*)(ws + OFF_HSUM);
    int*   tok    = (int*)(ws + OFF_TOK);
    float* wgt    = (float*)(ws + OFF_WGT);
    unsigned short* wt   = (unsigned short*)(ws + OFF_WT);
    unsigned short* ybuf = (unsigned short*)(ws + OFF_Y);

    hipFuncSetAttribute(reinterpret_cast<const void*>(moe_gemm_fast),
                        hipFuncAttributeMaxDynamicSharedMemorySize, 4 * SLOT_BYTES);
    hipFuncSetAttribute(reinterpret_cast<const void*>(moe_gemm_slow),
                        hipFuncAttributeMaxDynamicSharedMemorySize, 2 * SLBUF);

    hipMemsetAsync(d_out, 0, (size_t)out_size * sizeof(float), stream);
    hipMemsetAsync(d_ws, 0, OFF_ZERO_END, stream);

    wt_transpose<<<dim3(512, 8, 2), 256, 0, stream>>>(wgate, wup, wt);
    gating<<<256, 256, 0, stream>>>(x, gw, counts, fsum, psum, tok, wgt);
    build_work<<<1, 64, 0, stream>>>(counts, workv, nwork, fsum, psum,
                                     out + (size_t)T_TOK * DMODEL);

    bool fast = ws_size >= NEED_FAST;
    if (fast) {
        materialize<<<dim3(NWORK_MAX, 4), 256, 0, stream>>>(x, tok, wgt, counts, workv, nwork, ybuf);
        moe_gemm_fast<<<dim3(GRID_GEMM), 512, 4 * SLOT_BYTES, stream>>>(
            ybuf, wt, workv, nwork, hsum);
    } else {
        moe_gemm_slow<<<dim3(NWORK_MAX, HDIM / BN), 512, 2 * SLBUF, stream>>>(
            x, tok, wgt, wt, counts, workv, nwork, hsum);
    }

    down_proj<<<dim3(NEXP, DMODEL / 256), 256, 0, stream>>>(hsum, wdown, out);
}